// Round 4
// baseline (295.357 us; speedup 1.0000x reference)
//
#include <hip/hip_runtime.h>
#include <hip/hip_bf16.h>
#include <stdint.h>

// Problem constants: B=64, L=96, C=32, H=256, NL=2, K=3, TAU=2, VTH=1
// n = b*32 + c indexes the B*C=2048 "rows"; layer width H=256.

using short8  = __attribute__((ext_vector_type(8))) short;
using floatx4 = __attribute__((ext_vector_type(4))) float;

__device__ __forceinline__ unsigned short f2bf(float f) {
    unsigned int u = __float_as_uint(f);
    unsigned int r = u + 0x7fffu + ((u >> 16) & 1u);   // RNE
    return (unsigned short)(r >> 16);
}
__device__ __forceinline__ float bf2f(unsigned short h) {
    return __uint_as_float(((unsigned int)h) << 16);
}

// byte (8 spike bits) -> 8 bf16 halfwords (0x3F80 / 0x0000), ~14 VALU ops.
__device__ __forceinline__ uint4 expand8(unsigned int byte) {
    unsigned int lo = ((byte & 0xFu) * 0x00204081u) & 0x01010101u;
    unsigned int hi = (((byte >> 4) & 0xFu) * 0x00204081u) & 0x01010101u;
    uint4 d;
    d.x = __builtin_amdgcn_perm(0u, lo, 0x04010400u) * 0x3F80u;  // bits 0,1
    d.y = __builtin_amdgcn_perm(0u, lo, 0x04030402u) * 0x3F80u;  // bits 2,3
    d.z = __builtin_amdgcn_perm(0u, hi, 0x04010400u) * 0x3F80u;  // bits 4,5
    d.w = __builtin_amdgcn_perm(0u, hi, 0x04030402u) * 0x3F80u;  // bits 6,7
    return d;
}

// ---------------------------------------------------------------------------
// prep: per output-neuron o (256 blocks x 64 threads)
//  - W[o][k]  = sum_i w0[o,i]*w_enc[i,k]   (fp64)
//  - C0[o]    = sum_i b_enc[i]*w0[o,i] + b_rnn[0][o]  (fp64)
//  - split-3 bf16 decomposition of w1 row o into Bw[o][0..767]
// ---------------------------------------------------------------------------
__global__ void prep_kernel(const float* __restrict__ w_enc,
                            const float* __restrict__ b_enc,
                            const float* __restrict__ w_rnn,
                            const float* __restrict__ b_rnn,
                            double* __restrict__ Wd,
                            double* __restrict__ C0d,
                            unsigned short* __restrict__ Bw)
{
    const int o = blockIdx.x;
    const int lane = threadIdx.x;   // 64 threads
    const float4 w0v = *(const float4*)(w_rnn + (size_t)o * 256 + lane * 4);
    double a0 = 0.0, a1 = 0.0, a2 = 0.0, ab = 0.0;
#pragma unroll
    for (int e = 0; e < 4; ++e) {
        const int i = lane * 4 + e;
        const double wv = (double)(((const float*)&w0v)[e]);
        a0 += wv * (double)w_enc[i * 3 + 0];
        a1 += wv * (double)w_enc[i * 3 + 1];
        a2 += wv * (double)w_enc[i * 3 + 2];
        ab += wv * (double)b_enc[i];
    }
    for (int off = 32; off > 0; off >>= 1) {
        a0 += __shfl_down(a0, off, 64);
        a1 += __shfl_down(a1, off, 64);
        a2 += __shfl_down(a2, off, 64);
        ab += __shfl_down(ab, off, 64);
    }
    if (lane == 0) {
        Wd[o * 3 + 0] = a0;
        Wd[o * 3 + 1] = a1;
        Wd[o * 3 + 2] = a2;
        C0d[o] = ab + (double)b_rnn[o];
    }
    // split-3 of w1, exact: f == hi+mid+lo + r, |r| <= 2^-27 |f|
    const float4 w1v = *(const float4*)(w_rnn + 65536 + (size_t)o * 256 + lane * 4);
    ushort4 hi, mi, lo;
#pragma unroll
    for (int e = 0; e < 4; ++e) {
        float f = ((const float*)&w1v)[e];
        unsigned short h = f2bf(f);
        float r1 = f - bf2f(h);
        unsigned short mm = f2bf(r1);
        float r2 = r1 - bf2f(mm);
        unsigned short ll = f2bf(r2);
        ((unsigned short*)&hi)[e] = h;
        ((unsigned short*)&mi)[e] = mm;
        ((unsigned short*)&lo)[e] = ll;
    }
    *(ushort4*)(Bw + (size_t)o * 768 + lane * 4)       = hi;
    *(ushort4*)(Bw + (size_t)o * 768 + 256 + lane * 4) = mi;
    *(ushort4*)(Bw + (size_t)o * 768 + 512 + lane * 4) = lo;
}

// ---------------------------------------------------------------------------
// enc: layer-0 full scan. 2048 blocks x 256 threads. cur0 in fp64 (correctly
// rounded), membrane chain in exact reference fp32 op order. Spikes as
// ballots: s0b u64 index = (t*2048 + n)*4 + wave  (bit j <-> neuron 64w+j)
// ---------------------------------------------------------------------------
__global__ void enc_kernel(const float* __restrict__ inputs,
                           const double* __restrict__ Wd,
                           const double* __restrict__ C0d,
                           unsigned long long* __restrict__ s0b)
{
    const int n = blockIdx.x;
    const int tidx = threadIdx.x;
    const int b = n >> 5, c = n & 31;
    __shared__ float xr[98];
    if (tidx < 96)       xr[tidx + 1] = inputs[((size_t)b * 96 + tidx) * 32 + c];
    else if (tidx == 96) xr[0]  = 0.0f;
    else if (tidx == 97) xr[97] = 0.0f;
    __syncthreads();
    const double W0 = Wd[tidx * 3], W1 = Wd[tidx * 3 + 1], W2 = Wd[tidx * 3 + 2];
    const double c0 = C0d[tidx];
    const int wid = tidx >> 6, lane = tidx & 63;
    float v = 0.0f;
    for (int t = 0; t < 96; ++t) {
        float cur = (float)((double)xr[t] * W0 + (double)xr[t + 1] * W1 +
                            (double)xr[t + 2] * W2 + c0);
        float vv = v + (cur - v) * 0.5f;
        int sp = (vv - 1.0f) >= 0.0f;
        v = sp ? 0.0f : vv;
        unsigned long long bal = __ballot(sp);
        if (lane == 0) s0b[((size_t)t * 2048 + n) * 4 + wid] = bal;
    }
}

// ---------------------------------------------------------------------------
// rnn: layer-1, BARRIER-FREE. 2048 independent wave-jobs: 512 blocks x 4
// waves; wave = 16 rows x 16 cols. All 4 waves of a block share the same 16
// rows (rt = blockIdx>>2) so their mask loads hit L1; wave wid takes cols
// (blockIdx&3)*64 + wid*16. No LDS, no __syncthreads -> no vmcnt(0) drains:
// spike stores are fire-and-forget, mask loads prefetched 2 steps ahead.
// Each wave expands its own 8 A-frags in registers (~130 VALU, hides in the
// MFMA dep-latency gaps - separate issue pipes). Single accumulator chain,
// FP order identical to R1-R3 (absmax 0.0 preserved).
// MFMA A layout: A[m=lane&15][k=(lane>>4)*8+j]; C/D: col=lane&15,
// row=(lane>>4)*4+reg. Membrane update in exact reference fp32 op order.
// ---------------------------------------------------------------------------
__global__ __launch_bounds__(256, 2) void rnn_kernel(
    const unsigned char* __restrict__ s0b,
    const unsigned short* __restrict__ Bw,
    const float* __restrict__ b_rnn,
    float* __restrict__ out0,
    float* __restrict__ out1)
{
    const int tid  = threadIdx.x;
    const int wid  = tid >> 6, lane = tid & 63;
    const int m    = lane & 15, g = lane >> 4;
    const int g8   = g * 8;
    const int rt   = blockIdx.x >> 2;               // 128 row-tiles
    const int nw   = rt * 16;                       // block's 16 rows
    const int o0   = (blockIdx.x & 3) * 64 + wid * 16;  // wave's 16 cols

    // --- B fragments (loop-invariant): 24 ksteps x 4 VGPRs = 96 VGPRs ---
    short8 bfrag[24];
#pragma unroll
    for (int ks = 0; ks < 24; ++ks)
        bfrag[ks] = *(const short8*)(Bw + (size_t)(o0 + m) * 768 + ks * 32 + g8);
    const float bias = b_rnn[256 + o0 + m];

    // --- per-lane output pointers (C/D row = nw + g*4 + r) ---
    float* pr[4];
    int    row_r[4];
#pragma unroll
    for (int r = 0; r < 4; ++r) {
        const int row = nw + g * 4 + r;
        row_r[r] = row;
        pr[r] = out0 + ((size_t)(row >> 5) * 96) * 8192 + (size_t)(row & 31) * 256
                     + o0 + m;
    }

    // --- mask stream: lane reads full 32B mask of A-row (nw + m), 2 ahead ---
    const unsigned char* mbase = s0b + ((size_t)(nw + m)) * 32;
    uint4 ma0 = *(const uint4*)(mbase);
    uint4 mb0 = *(const uint4*)(mbase + 16);
    uint4 ma1 = *(const uint4*)(mbase + 65536);
    uint4 mb1 = *(const uint4*)(mbase + 65536 + 16);

    floatx4 v = {0.f, 0.f, 0.f, 0.f};

#pragma unroll 2
    for (int t = 0; t < 96; ++t) {
        // prefetch t+2 (fire now, consumed two iterations later)
        uint4 pa = ma1, pb = mb1;
        if (t < 94) {
            const unsigned char* q = mbase + (size_t)(t + 2) * 65536;
            ma1 = *(const uint4*)q;
            mb1 = *(const uint4*)(q + 16);
        }

        // expand this wave's 8 A-fragments from the t-mask in registers
        unsigned int w32[8] = {ma0.x, ma0.y, ma0.z, ma0.w,
                               mb0.x, mb0.y, mb0.z, mb0.w};
        short8 af[8];
#pragma unroll
        for (int f = 0; f < 8; ++f) {
            uint4 e = expand8((w32[f] >> g8) & 0xFFu);
            af[f] = *(short8*)&e;
        }

        // GEMM: cur1 tile = spikes @ (w1_hi; w1_mid; w1_lo)
        floatx4 acc = {0.f, 0.f, 0.f, 0.f};
#pragma unroll
        for (int ks = 0; ks < 24; ++ks)
            acc = __builtin_amdgcn_mfma_f32_16x16x32_bf16(af[ks & 7], bfrag[ks], acc, 0, 0, 0);

        // membrane update (exact reference fp32 op order) + direct store
#pragma unroll
        for (int r = 0; r < 4; ++r) {
            float cur = acc[r] + bias;
            float vv = v[r];
            vv = vv + (cur - vv) * 0.5f;
            float s = ((vv - 1.0f) >= 0.0f) ? 1.0f : 0.0f;
            v[r] = vv * (1.0f - s);
            pr[r][(size_t)t * 8192] = s;
            if (t == 95)
                out1[(size_t)row_r[r] * 256 + o0 + m] = s;
        }
        ma0 = pa; mb0 = pb;
    }
}

// ---------------------------------------------------------------------------
extern "C" void kernel_launch(void* const* d_in, const int* in_sizes, int n_in,
                              void* d_out, int out_size, void* d_ws, size_t ws_size,
                              hipStream_t stream) {
    const float* inputs = (const float*)d_in[0];   // [64,96,32]
    const float* w_enc  = (const float*)d_in[1];   // [256,1,3]
    const float* b_enc  = (const float*)d_in[2];   // [256]
    const float* w_rnn  = (const float*)d_in[3];   // [2,256,256]
    const float* b_rnn  = (const float*)d_in[4];   // [2,256]

    float* out0 = (float*)d_out;                       // [64,96,8192]
    float* out1 = out0 + (size_t)64 * 96 * 8192;       // [64,8192]

    char* ws = (char*)d_ws;
    double*         Wd  = (double*)(ws);               //  768 doubles  [0,6144)
    double*         C0d = (double*)(ws + 6144);        //  256 doubles  [6144,8192)
    unsigned short* Bw  = (unsigned short*)(ws + 8192);// 256*768 u16   [8192,401408)
    char*           s0b = ws + 401408;                 // 6291456 bytes of spike bits

    prep_kernel<<<256, 64, 0, stream>>>(w_enc, b_enc, w_rnn, b_rnn, Wd, C0d, Bw);
    enc_kernel<<<2048, 256, 0, stream>>>(inputs, Wd, C0d, (unsigned long long*)s0b);
    rnn_kernel<<<512, 256, 0, stream>>>((const unsigned char*)s0b, Bw, b_rnn, out0, out1);
}

// Round 5
// 271.180 us; speedup vs baseline: 1.0892x; 1.0892x over previous
//
#include <hip/hip_runtime.h>
#include <hip/hip_bf16.h>
#include <stdint.h>

// Problem constants: B=64, L=96, C=32, H=256, NL=2, K=3, TAU=2, VTH=1
// n = b*32 + c indexes the B*C=2048 "rows"; layer width H=256.

using short8  = __attribute__((ext_vector_type(8))) short;
using floatx4 = __attribute__((ext_vector_type(4))) float;

__device__ __forceinline__ unsigned short f2bf(float f) {
    unsigned int u = __float_as_uint(f);
    unsigned int r = u + 0x7fffu + ((u >> 16) & 1u);   // RNE
    return (unsigned short)(r >> 16);
}
__device__ __forceinline__ float bf2f(unsigned short h) {
    return __uint_as_float(((unsigned int)h) << 16);
}

// byte (8 spike bits) -> 8 bf16 halfwords (0x3F80 / 0x0000), ~14 VALU ops.
__device__ __forceinline__ uint4 expand8(unsigned int byte) {
    unsigned int lo = ((byte & 0xFu) * 0x00204081u) & 0x01010101u;
    unsigned int hi = (((byte >> 4) & 0xFu) * 0x00204081u) & 0x01010101u;
    uint4 d;
    d.x = __builtin_amdgcn_perm(0u, lo, 0x04010400u) * 0x3F80u;  // bits 0,1
    d.y = __builtin_amdgcn_perm(0u, lo, 0x04030402u) * 0x3F80u;  // bits 2,3
    d.z = __builtin_amdgcn_perm(0u, hi, 0x04010400u) * 0x3F80u;  // bits 4,5
    d.w = __builtin_amdgcn_perm(0u, hi, 0x04030402u) * 0x3F80u;  // bits 6,7
    return d;
}

// ---------------------------------------------------------------------------
// prep: per output-neuron o (256 blocks x 64 threads)
//  - W[o][k]  = sum_i w0[o,i]*w_enc[i,k]   (fp64)
//  - C0[o]    = sum_i b_enc[i]*w0[o,i] + b_rnn[0][o]  (fp64)
//  - split-3 bf16 decomposition of w1 row o into Bw[o][0..767]
// ---------------------------------------------------------------------------
__global__ void prep_kernel(const float* __restrict__ w_enc,
                            const float* __restrict__ b_enc,
                            const float* __restrict__ w_rnn,
                            const float* __restrict__ b_rnn,
                            double* __restrict__ Wd,
                            double* __restrict__ C0d,
                            unsigned short* __restrict__ Bw)
{
    const int o = blockIdx.x;
    const int lane = threadIdx.x;   // 64 threads
    const float4 w0v = *(const float4*)(w_rnn + (size_t)o * 256 + lane * 4);
    double a0 = 0.0, a1 = 0.0, a2 = 0.0, ab = 0.0;
#pragma unroll
    for (int e = 0; e < 4; ++e) {
        const int i = lane * 4 + e;
        const double wv = (double)(((const float*)&w0v)[e]);
        a0 += wv * (double)w_enc[i * 3 + 0];
        a1 += wv * (double)w_enc[i * 3 + 1];
        a2 += wv * (double)w_enc[i * 3 + 2];
        ab += wv * (double)b_enc[i];
    }
    for (int off = 32; off > 0; off >>= 1) {
        a0 += __shfl_down(a0, off, 64);
        a1 += __shfl_down(a1, off, 64);
        a2 += __shfl_down(a2, off, 64);
        ab += __shfl_down(ab, off, 64);
    }
    if (lane == 0) {
        Wd[o * 3 + 0] = a0;
        Wd[o * 3 + 1] = a1;
        Wd[o * 3 + 2] = a2;
        C0d[o] = ab + (double)b_rnn[o];
    }
    // split-3 of w1, exact: f == hi+mid+lo + r, |r| <= 2^-27 |f|
    const float4 w1v = *(const float4*)(w_rnn + 65536 + (size_t)o * 256 + lane * 4);
    ushort4 hi, mi, lo;
#pragma unroll
    for (int e = 0; e < 4; ++e) {
        float f = ((const float*)&w1v)[e];
        unsigned short h = f2bf(f);
        float r1 = f - bf2f(h);
        unsigned short mm = f2bf(r1);
        float r2 = r1 - bf2f(mm);
        unsigned short ll = f2bf(r2);
        ((unsigned short*)&hi)[e] = h;
        ((unsigned short*)&mi)[e] = mm;
        ((unsigned short*)&lo)[e] = ll;
    }
    *(ushort4*)(Bw + (size_t)o * 768 + lane * 4)       = hi;
    *(ushort4*)(Bw + (size_t)o * 768 + 256 + lane * 4) = mi;
    *(ushort4*)(Bw + (size_t)o * 768 + 512 + lane * 4) = lo;
}

// ---------------------------------------------------------------------------
// enc: layer-0 full scan. 2048 blocks x 256 threads. cur0 in fp64 (correctly
// rounded), membrane chain in exact reference fp32 op order. Spikes as
// ballots: s0b u64 index = (t*2048 + n)*4 + wave  (bit j <-> neuron 64w+j)
// ---------------------------------------------------------------------------
__global__ void enc_kernel(const float* __restrict__ inputs,
                           const double* __restrict__ Wd,
                           const double* __restrict__ C0d,
                           unsigned long long* __restrict__ s0b)
{
    const int n = blockIdx.x;
    const int tidx = threadIdx.x;
    const int b = n >> 5, c = n & 31;
    __shared__ float xr[98];
    if (tidx < 96)       xr[tidx + 1] = inputs[((size_t)b * 96 + tidx) * 32 + c];
    else if (tidx == 96) xr[0]  = 0.0f;
    else if (tidx == 97) xr[97] = 0.0f;
    __syncthreads();
    const double W0 = Wd[tidx * 3], W1 = Wd[tidx * 3 + 1], W2 = Wd[tidx * 3 + 2];
    const double c0 = C0d[tidx];
    const int wid = tidx >> 6, lane = tidx & 63;
    float v = 0.0f;
    for (int t = 0; t < 96; ++t) {
        float cur = (float)((double)xr[t] * W0 + (double)xr[t + 1] * W1 +
                            (double)xr[t + 2] * W2 + c0);
        float vv = v + (cur - v) * 0.5f;
        int sp = (vv - 1.0f) >= 0.0f;
        v = sp ? 0.0f : vv;
        unsigned long long bal = __ballot(sp);
        if (lane == 0) s0b[((size_t)t * 2048 + n) * 4 + wid] = bal;
    }
}

// ---------------------------------------------------------------------------
// rnn: layer-1. grid 512 = 128 row-tiles x 4 col-groups; block = 4 waves,
// 16 rows x 64 cols; wave w owns cols [cg*64 + w*16, +16).
// A-fragments shared across waves via double-buffered LDS (expand t+1 while
// computing t). R5 change vs the 77us R1 champion: the per-t sync is a RAW
// "s_waitcnt lgkmcnt(0); s_barrier" (inline asm) instead of __syncthreads().
// lgkmcnt(0) orders the LDS producer->consumer handoff; vmcnt is NEVER
// drained, so the per-t spike stores (which nothing reads) stay in flight
// across barriers instead of serializing ~300+ cyc of store-ack per step.
// Race safety: ebuf double-buffered; each wave's own ds ops retired at its
// lgkmcnt(0) before s_barrier => visible CU-wide after the barrier.
// MFMA A layout: A[m=lane&15][k=(lane>>4)*8+j]; C/D: col=lane&15,
// row=(lane>>4)*4+reg. Membrane update in exact reference fp32 op order.
// ---------------------------------------------------------------------------
__global__ __launch_bounds__(256, 2) void rnn_kernel(
    const unsigned char* __restrict__ s0b,
    const unsigned short* __restrict__ Bw,
    const float* __restrict__ b_rnn,
    float* __restrict__ out0,
    float* __restrict__ out1)
{
    const int tid  = threadIdx.x;
    const int wid  = tid >> 6, lane = tid & 63;
    const int m    = lane & 15, g = lane >> 4;
    const int g8   = g * 8;
    const int rt   = blockIdx.x >> 2, cg = blockIdx.x & 3;
    const int nw   = rt * 16;                 // block's 16 rows
    const int o0   = cg * 64 + wid * 16;      // this wave's 16 cols

    __shared__ unsigned char ebuf[2][8192];   // 8 A-frags x 1KB, double-buffered

    // --- B fragments (loop-invariant): 24 ksteps x 4 VGPRs = 96 VGPRs ---
    short8 bfrag[24];
#pragma unroll
    for (int ks = 0; ks < 24; ++ks)
        bfrag[ks] = *(const short8*)(Bw + (size_t)(o0 + m) * 768 + ks * 32 + g8);
    const float bias = b_rnn[256 + o0 + m];

    // --- per-lane output pointers (C/D row = nw + g*4 + r) ---
    float* pr[4];
    int    row_r[4];
#pragma unroll
    for (int r = 0; r < 4; ++r) {
        const int row = nw + g * 4 + r;
        row_r[r] = row;
        pr[r] = out0 + ((size_t)(row >> 5) * 96) * 8192 + (size_t)(row & 31) * 256
                     + o0 + m;
    }

    // --- mask loader: producer lane handles row nw + m, dwords [2w, 2w+1] ---
    const unsigned char* mbase = s0b + ((size_t)(nw + m)) * 32 + wid * 8;
    #define LOADM(T) (*(const uint2*)(mbase + (size_t)(T) * 65536))

    // preamble: expand t=0 into ebuf[0]; fetch masks for t=1
    {
        uint2 m0 = LOADM(0);
        *(uint4*)(ebuf[0] + (2 * wid) * 1024 + lane * 16)     = expand8((m0.x >> g8) & 0xFFu);
        *(uint4*)(ebuf[0] + (2 * wid + 1) * 1024 + lane * 16) = expand8((m0.y >> g8) & 0xFFu);
    }
    uint2 mB = LOADM(1);

    floatx4 v = {0.f, 0.f, 0.f, 0.f};

    for (int t = 0; t < 96; ++t) {
        const int p = t & 1;
        // LDS-only barrier: order ds writes/reads, leave global stores in flight
        asm volatile("s_waitcnt lgkmcnt(0)\n\ts_barrier" ::: "memory");
        uint2 mC = LOADM(t + 2 < 96 ? t + 2 : 95);   // prefetch

        // consume A fragments of timestep t
        short8 af[8];
#pragma unroll
        for (int f = 0; f < 8; ++f)
            af[f] = *(const short8*)(ebuf[p] + f * 1024 + lane * 16);

        // produce A fragments of timestep t+1 into ebuf[1-p]
        if (t < 95) {
            *(uint4*)(ebuf[1 - p] + (2 * wid) * 1024 + lane * 16)     = expand8((mB.x >> g8) & 0xFFu);
            *(uint4*)(ebuf[1 - p] + (2 * wid + 1) * 1024 + lane * 16) = expand8((mB.y >> g8) & 0xFFu);
        }

        // GEMM: cur1 tile = spikes @ (w1_hi; w1_mid; w1_lo)
        floatx4 acc = {0.f, 0.f, 0.f, 0.f};
#pragma unroll
        for (int ks = 0; ks < 24; ++ks)
            acc = __builtin_amdgcn_mfma_f32_16x16x32_bf16(af[ks & 7], bfrag[ks], acc, 0, 0, 0);

        // membrane update (exact reference fp32 op order) + direct store
#pragma unroll
        for (int r = 0; r < 4; ++r) {
            float cur = acc[r] + bias;
            float vv = v[r];
            vv = vv + (cur - vv) * 0.5f;
            float s = ((vv - 1.0f) >= 0.0f) ? 1.0f : 0.0f;
            v[r] = vv * (1.0f - s);
            pr[r][(size_t)t * 8192] = s;
            if (t == 95)
                out1[(size_t)row_r[r] * 256 + o0 + m] = s;
        }
        mB = mC;
    }
    #undef LOADM
}

// ---------------------------------------------------------------------------
extern "C" void kernel_launch(void* const* d_in, const int* in_sizes, int n_in,
                              void* d_out, int out_size, void* d_ws, size_t ws_size,
                              hipStream_t stream) {
    const float* inputs = (const float*)d_in[0];   // [64,96,32]
    const float* w_enc  = (const float*)d_in[1];   // [256,1,3]
    const float* b_enc  = (const float*)d_in[2];   // [256]
    const float* w_rnn  = (const float*)d_in[3];   // [2,256,256]
    const float* b_rnn  = (const float*)d_in[4];   // [2,256]

    float* out0 = (float*)d_out;                       // [64,96,8192]
    float* out1 = out0 + (size_t)64 * 96 * 8192;       // [64,8192]

    char* ws = (char*)d_ws;
    double*         Wd  = (double*)(ws);               //  768 doubles  [0,6144)
    double*         C0d = (double*)(ws + 6144);        //  256 doubles  [6144,8192)
    unsigned short* Bw  = (unsigned short*)(ws + 8192);// 256*768 u16   [8192,401408)
    char*           s0b = ws + 401408;                 // 6291456 bytes of spike bits

    prep_kernel<<<256, 64, 0, stream>>>(w_enc, b_enc, w_rnn, b_rnn, Wd, C0d, Bw);
    enc_kernel<<<2048, 256, 0, stream>>>(inputs, Wd, C0d, (unsigned long long*)s0b);
    rnn_kernel<<<512, 256, 0, stream>>>((const unsigned char*)s0b, Bw, b_rnn, out0, out1);
}

// Round 6
// 262.177 us; speedup vs baseline: 1.1266x; 1.0343x over previous
//
#include <hip/hip_runtime.h>
#include <hip/hip_bf16.h>
#include <stdint.h>

// Problem constants: B=64, L=96, C=32, H=256, NL=2, K=3, TAU=2, VTH=1
// n = b*32 + c indexes the B*C=2048 "rows"; layer width H=256.

using floatx4 = __attribute__((ext_vector_type(4))) float;
using intx4   = __attribute__((ext_vector_type(4))) int;

// ---------------------------------------------------------------------------
// prep: per output-neuron o (256 blocks x 64 threads)
//  - W[o][k]  = sum_i w0[o,i]*w_enc[i,k]   (fp64)
//  - C0[o]    = sum_i b_enc[i]*w0[o,i] + b_rnn[0][o]  (fp64)
//  - i8 4-limb digit planes of w1: q=rn(w*2^27), q=((d0*128+d1)*128+d2)*128+d3,
//    digits in [-64,63]. Bw8[o][l][k] = d_l of w1[o][k]. EXACT (|w|<1).
// ---------------------------------------------------------------------------
__global__ void prep_kernel(const float* __restrict__ w_enc,
                            const float* __restrict__ b_enc,
                            const float* __restrict__ w_rnn,
                            const float* __restrict__ b_rnn,
                            double* __restrict__ Wd,
                            double* __restrict__ C0d,
                            signed char* __restrict__ Bw8)
{
    const int o = blockIdx.x;
    const int lane = threadIdx.x;   // 64 threads
    const float4 w0v = *(const float4*)(w_rnn + (size_t)o * 256 + lane * 4);
    double a0 = 0.0, a1 = 0.0, a2 = 0.0, ab = 0.0;
#pragma unroll
    for (int e = 0; e < 4; ++e) {
        const int i = lane * 4 + e;
        const double wv = (double)(((const float*)&w0v)[e]);
        a0 += wv * (double)w_enc[i * 3 + 0];
        a1 += wv * (double)w_enc[i * 3 + 1];
        a2 += wv * (double)w_enc[i * 3 + 2];
        ab += wv * (double)b_enc[i];
    }
    for (int off = 32; off > 0; off >>= 1) {
        a0 += __shfl_down(a0, off, 64);
        a1 += __shfl_down(a1, off, 64);
        a2 += __shfl_down(a2, off, 64);
        ab += __shfl_down(ab, off, 64);
    }
    if (lane == 0) {
        Wd[o * 3 + 0] = a0;
        Wd[o * 3 + 1] = a1;
        Wd[o * 3 + 2] = a2;
        C0d[o] = ab + (double)b_rnn[o];
    }
    // i8 digit planes of w1 (layer-1), 4 consecutive k per lane
    const float4 w1v = *(const float4*)(w_rnn + 65536 + (size_t)o * 256 + lane * 4);
    unsigned int pack[4] = {0u, 0u, 0u, 0u};   // pack[l]: digits for e=0..3
#pragma unroll
    for (int e = 0; e < 4; ++e) {
        float f = ((const float*)&w1v)[e];
        int q = __double2int_rn((double)f * 134217728.0);   // w * 2^27, |q| <= 2^27
        int d3 = ((q + 64) & 127) - 64;  q = (q - d3) >> 7;
        int d2 = ((q + 64) & 127) - 64;  q = (q - d2) >> 7;
        int d1 = ((q + 64) & 127) - 64;  q = (q - d1) >> 7;
        int d0 = q;                       // |d0| <= 64
        pack[0] |= ((unsigned int)(d0 & 0xFF)) << (8 * e);
        pack[1] |= ((unsigned int)(d1 & 0xFF)) << (8 * e);
        pack[2] |= ((unsigned int)(d2 & 0xFF)) << (8 * e);
        pack[3] |= ((unsigned int)(d3 & 0xFF)) << (8 * e);
    }
#pragma unroll
    for (int l = 0; l < 4; ++l)
        *(unsigned int*)(Bw8 + ((size_t)o * 4 + l) * 256 + lane * 4) = pack[l];
}

// ---------------------------------------------------------------------------
// enc: layer-0 full scan. 2048 blocks x 256 threads. cur0 in fp64 (correctly
// rounded), membrane chain in exact reference fp32 op order. Spike mask rows
// stored HALFWORD-TRANSPOSED: row (t,n) is 32B; global halfword h=i/16
// (h = 4*wave + j) lands at byte offset 8*j + 2*wave. Then rnn lane (g,m)
// reads one aligned uint2 at +8g = halfwords {4c+g : c=0..3} = exactly the
// k-bits its 4 MFMA chunks need.
// ---------------------------------------------------------------------------
__global__ void enc_kernel(const float* __restrict__ inputs,
                           const double* __restrict__ Wd,
                           const double* __restrict__ C0d,
                           unsigned char* __restrict__ s0b)
{
    const int n = blockIdx.x;
    const int tidx = threadIdx.x;
    const int b = n >> 5, c = n & 31;
    __shared__ float xr[98];
    if (tidx < 96)       xr[tidx + 1] = inputs[((size_t)b * 96 + tidx) * 32 + c];
    else if (tidx == 96) xr[0]  = 0.0f;
    else if (tidx == 97) xr[97] = 0.0f;
    __syncthreads();
    const double W0 = Wd[tidx * 3], W1 = Wd[tidx * 3 + 1], W2 = Wd[tidx * 3 + 2];
    const double c0 = C0d[tidx];
    const int wid = tidx >> 6, lane = tidx & 63;
    float v = 0.0f;
    for (int t = 0; t < 96; ++t) {
        float cur = (float)((double)xr[t] * W0 + (double)xr[t + 1] * W1 +
                            (double)xr[t + 2] * W2 + c0);
        float vv = v + (cur - v) * 0.5f;
        int sp = (vv - 1.0f) >= 0.0f;
        v = sp ? 0.0f : vv;
        unsigned long long bal = __ballot(sp);
        if ((lane & 15) == 0) {
            const int j = lane >> 4;
            *(unsigned short*)(s0b + ((size_t)t * 2048 + n) * 32 + 8 * j + 2 * wid)
                = (unsigned short)(bal >> (16 * j));
        }
    }
}

// ---------------------------------------------------------------------------
// rnn: layer-1, i8 4-limb exact MFMA, NO LDS, NO barriers. 2048 independent
// wave-jobs (512 blocks x 4 waves); wave = 16 rows x 16 cols; the 4 waves of
// a block share the same 16 rows (L1 mask reuse). Per t: one uint2 mask read
// per lane (transposed layout), bits -> 0/1 i8 bytes (~60 VALU), 16 MFMAs as
// 4 INDEPENDENT limb chains of length 4, exact fp64 limb-combine, membrane
// update in exact reference fp32 op order, fire-and-forget stores.
// C/D layout 16x16: col=lane&15, row=(lane>>4)*4+reg (dtype-independent).
// A/B k-packing is self-consistent across operands (k = 64c + 16g + bytepos).
// ---------------------------------------------------------------------------
__global__ __launch_bounds__(256, 2) void rnn_kernel(
    const unsigned char* __restrict__ s0b,
    const signed char* __restrict__ Bw8,
    const float* __restrict__ b_rnn,
    float* __restrict__ out0,
    float* __restrict__ out1)
{
    const int tid  = threadIdx.x;
    const int wid  = tid >> 6, lane = tid & 63;
    const int m    = lane & 15, g = lane >> 4;
    const int job  = blockIdx.x * 4 + wid;          // 2048 jobs
    const int rt   = job >> 4;                      // 128 row-tiles
    const int nw   = rt * 16;
    const int o0   = (job & 15) * 16;               // 16 col-tiles

    // --- B fragments (loop-invariant): 4 limbs x 4 chunks x int4 = 64 VGPRs
    intx4 bfrag[4][4];
#pragma unroll
    for (int l = 0; l < 4; ++l)
#pragma unroll
        for (int c = 0; c < 4; ++c)
            bfrag[l][c] = *(const intx4*)(Bw8 + ((size_t)(o0 + m) * 4 + l) * 256
                                               + c * 64 + g * 16);
    const float bias = b_rnn[256 + o0 + m];

    // --- per-lane output pointers (C/D row = nw + g*4 + r) ---
    float* pr[4];
    int    row_r[4];
#pragma unroll
    for (int r = 0; r < 4; ++r) {
        const int row = nw + g * 4 + r;
        row_r[r] = row;
        pr[r] = out0 + ((size_t)(row >> 5) * 96) * 8192 + (size_t)(row & 31) * 256
                     + o0 + m;
    }

    // --- mask stream: lane reads uint2 at row*32 + 8g, prefetched 2 ahead ---
    const unsigned char* mp = s0b + ((size_t)(nw + m)) * 32 + 8 * g;
    uint2 m0 = *(const uint2*)(mp);
    uint2 m1 = *(const uint2*)(mp + 65536);

    floatx4 v = {0.f, 0.f, 0.f, 0.f};

    for (int t = 0; t < 96; ++t) {
        uint2 pa = m1;
        if (t < 94)
            m1 = *(const uint2*)(mp + (size_t)(t + 2) * 65536);

        // extract the 4 chunk-halfwords, expand bits -> 0/1 bytes
        unsigned int hw[4] = { m0.x & 0xFFFFu, m0.x >> 16,
                               m0.y & 0xFFFFu, m0.y >> 16 };
        intx4 af[4];
#pragma unroll
        for (int c = 0; c < 4; ++c) {
            unsigned int h = hw[c];
            intx4 a;
            a.x = (int)((( h        & 0xFu) * 0x00204081u) & 0x01010101u);
            a.y = (int)((((h >> 4)  & 0xFu) * 0x00204081u) & 0x01010101u);
            a.z = (int)((((h >> 8)  & 0xFu) * 0x00204081u) & 0x01010101u);
            a.w = (int)((((h >> 12) & 0xFu) * 0x00204081u) & 0x01010101u);
            af[c] = a;
        }

        // 4 independent limb chains, 4 MFMAs each (K=256 per limb)
        intx4 acc0 = {0,0,0,0}, acc1 = {0,0,0,0}, acc2 = {0,0,0,0}, acc3 = {0,0,0,0};
#pragma unroll
        for (int c = 0; c < 4; ++c) {
            acc0 = __builtin_amdgcn_mfma_i32_16x16x64_i8(af[c], bfrag[0][c], acc0, 0, 0, 0);
            acc1 = __builtin_amdgcn_mfma_i32_16x16x64_i8(af[c], bfrag[1][c], acc1, 0, 0, 0);
            acc2 = __builtin_amdgcn_mfma_i32_16x16x64_i8(af[c], bfrag[2][c], acc2, 0, 0, 0);
            acc3 = __builtin_amdgcn_mfma_i32_16x16x64_i8(af[c], bfrag[3][c], acc3, 0, 0, 0);
        }

        // exact limb combine + membrane update (reference fp32 op order)
#pragma unroll
        for (int r = 0; r < 4; ++r) {
            int a01 = acc0[r] * 128 + acc1[r];      // exact, |.| < 2^21
            int a23 = acc2[r] * 128 + acc3[r];
            double dd = (double)a01 * 16384.0 + (double)a23;   // exact
            float cur = (float)(dd * 7.450580596923828125e-9) + bias;  // *2^-27
            float vv = v[r];
            vv = vv + (cur - vv) * 0.5f;
            float s = ((vv - 1.0f) >= 0.0f) ? 1.0f : 0.0f;
            v[r] = vv * (1.0f - s);
            pr[r][(size_t)t * 8192] = s;
            if (t == 95)
                out1[(size_t)row_r[r] * 256 + o0 + m] = s;
        }
        m0 = pa;
    }
}

// ---------------------------------------------------------------------------
extern "C" void kernel_launch(void* const* d_in, const int* in_sizes, int n_in,
                              void* d_out, int out_size, void* d_ws, size_t ws_size,
                              hipStream_t stream) {
    const float* inputs = (const float*)d_in[0];   // [64,96,32]
    const float* w_enc  = (const float*)d_in[1];   // [256,1,3]
    const float* b_enc  = (const float*)d_in[2];   // [256]
    const float* w_rnn  = (const float*)d_in[3];   // [2,256,256]
    const float* b_rnn  = (const float*)d_in[4];   // [2,256]

    float* out0 = (float*)d_out;                       // [64,96,8192]
    float* out1 = out0 + (size_t)64 * 96 * 8192;       // [64,8192]

    char* ws = (char*)d_ws;
    double*      Wd  = (double*)(ws);                  //  768 doubles  [0,6144)
    double*      C0d = (double*)(ws + 6144);           //  256 doubles  [6144,8192)
    signed char* Bw8 = (signed char*)(ws + 8192);      //  256*4*256 i8 [8192,270336)
    unsigned char* s0b = (unsigned char*)(ws + 270336);// 6291456 bytes of spike bits

    prep_kernel<<<256, 64, 0, stream>>>(w_enc, b_enc, w_rnn, b_rnn, Wd, C0d, Bw8);
    enc_kernel<<<2048, 256, 0, stream>>>(inputs, Wd, C0d, s0b);
    rnn_kernel<<<512, 256, 0, stream>>>(s0b, Bw8, b_rnn, out0, out1);
}

// Round 7
// 260.862 us; speedup vs baseline: 1.1322x; 1.0050x over previous
//
#include <hip/hip_runtime.h>
#include <hip/hip_bf16.h>
#include <stdint.h>

// Problem constants: B=64, L=96, C=32, H=256, NL=2, K=3, TAU=2, VTH=1
// n = b*32 + c indexes the B*C=2048 "rows"; layer width H=256.

using floatx4 = __attribute__((ext_vector_type(4))) float;
using intx4   = __attribute__((ext_vector_type(4))) int;

// ---------------------------------------------------------------------------
// prep: per output-neuron o (256 blocks x 64 threads)
//  - W[o][k]  = sum_i w0[o,i]*w_enc[i,k]   (fp64)
//  - C0[o]    = sum_i b_enc[i]*w0[o,i] + b_rnn[0][o]  (fp64)
//  - i8 4-limb digit planes of w1: q=rn(w*2^27), q=((d0*128+d1)*128+d2)*128+d3,
//    digits in [-64,63]. Bw8[o][l][k] = d_l of w1[o][k]. EXACT (|w|<1).
// ---------------------------------------------------------------------------
__global__ void prep_kernel(const float* __restrict__ w_enc,
                            const float* __restrict__ b_enc,
                            const float* __restrict__ w_rnn,
                            const float* __restrict__ b_rnn,
                            double* __restrict__ Wd,
                            double* __restrict__ C0d,
                            signed char* __restrict__ Bw8)
{
    const int o = blockIdx.x;
    const int lane = threadIdx.x;   // 64 threads
    const float4 w0v = *(const float4*)(w_rnn + (size_t)o * 256 + lane * 4);
    double a0 = 0.0, a1 = 0.0, a2 = 0.0, ab = 0.0;
#pragma unroll
    for (int e = 0; e < 4; ++e) {
        const int i = lane * 4 + e;
        const double wv = (double)(((const float*)&w0v)[e]);
        a0 += wv * (double)w_enc[i * 3 + 0];
        a1 += wv * (double)w_enc[i * 3 + 1];
        a2 += wv * (double)w_enc[i * 3 + 2];
        ab += wv * (double)b_enc[i];
    }
    for (int off = 32; off > 0; off >>= 1) {
        a0 += __shfl_down(a0, off, 64);
        a1 += __shfl_down(a1, off, 64);
        a2 += __shfl_down(a2, off, 64);
        ab += __shfl_down(ab, off, 64);
    }
    if (lane == 0) {
        Wd[o * 3 + 0] = a0;
        Wd[o * 3 + 1] = a1;
        Wd[o * 3 + 2] = a2;
        C0d[o] = ab + (double)b_rnn[o];
    }
    // i8 digit planes of w1 (layer-1), 4 consecutive k per lane
    const float4 w1v = *(const float4*)(w_rnn + 65536 + (size_t)o * 256 + lane * 4);
    unsigned int pack[4] = {0u, 0u, 0u, 0u};   // pack[l]: digits for e=0..3
#pragma unroll
    for (int e = 0; e < 4; ++e) {
        float f = ((const float*)&w1v)[e];
        int q = __double2int_rn((double)f * 134217728.0);   // w * 2^27, |q| <= 2^27
        int d3 = ((q + 64) & 127) - 64;  q = (q - d3) >> 7;
        int d2 = ((q + 64) & 127) - 64;  q = (q - d2) >> 7;
        int d1 = ((q + 64) & 127) - 64;  q = (q - d1) >> 7;
        int d0 = q;                       // |d0| <= 64
        pack[0] |= ((unsigned int)(d0 & 0xFF)) << (8 * e);
        pack[1] |= ((unsigned int)(d1 & 0xFF)) << (8 * e);
        pack[2] |= ((unsigned int)(d2 & 0xFF)) << (8 * e);
        pack[3] |= ((unsigned int)(d3 & 0xFF)) << (8 * e);
    }
#pragma unroll
    for (int l = 0; l < 4; ++l)
        *(unsigned int*)(Bw8 + ((size_t)o * 4 + l) * 256 + lane * 4) = pack[l];
}

// ---------------------------------------------------------------------------
// enc: layer-0 full scan. 2048 blocks x 256 threads. cur0 in fp64 (correctly
// rounded), membrane chain in exact reference fp32 op order. Spike mask rows
// stored HALFWORD-TRANSPOSED: row (t,n) is 32B; global halfword h=i/16
// (h = 4*wave + j) lands at byte offset 8*j + 2*wave. Then rnn lane (g,m)
// reads one aligned uint2 at +8g = halfwords {4c+g : c=0..3} = exactly the
// k-bits its 4 MFMA chunks need.
// ---------------------------------------------------------------------------
__global__ void enc_kernel(const float* __restrict__ inputs,
                           const double* __restrict__ Wd,
                           const double* __restrict__ C0d,
                           unsigned char* __restrict__ s0b)
{
    const int n = blockIdx.x;
    const int tidx = threadIdx.x;
    const int b = n >> 5, c = n & 31;
    __shared__ float xr[98];
    if (tidx < 96)       xr[tidx + 1] = inputs[((size_t)b * 96 + tidx) * 32 + c];
    else if (tidx == 96) xr[0]  = 0.0f;
    else if (tidx == 97) xr[97] = 0.0f;
    __syncthreads();
    const double W0 = Wd[tidx * 3], W1 = Wd[tidx * 3 + 1], W2 = Wd[tidx * 3 + 2];
    const double c0 = C0d[tidx];
    const int wid = tidx >> 6, lane = tidx & 63;
    float v = 0.0f;
    for (int t = 0; t < 96; ++t) {
        float cur = (float)((double)xr[t] * W0 + (double)xr[t + 1] * W1 +
                            (double)xr[t + 2] * W2 + c0);
        float vv = v + (cur - v) * 0.5f;
        int sp = (vv - 1.0f) >= 0.0f;
        v = sp ? 0.0f : vv;
        unsigned long long bal = __ballot(sp);
        if ((lane & 15) == 0) {
            const int j = lane >> 4;
            *(unsigned short*)(s0b + ((size_t)t * 2048 + n) * 32 + 8 * j + 2 * wid)
                = (unsigned short)(bal >> (16 * j));
        }
    }
}

// ---------------------------------------------------------------------------
// rnn: layer-1, i8 4-limb exact MFMA, NO LDS, NO barriers. 2048 independent
// wave-jobs (512 blocks x 4 waves); wave = 16 rows x 16 cols; the 4 waves of
// a block share the same 16 rows (L1 mask reuse). R7: register-pressure diet
// to fit the 128-VGPR cap of __launch_bounds__(256,2) with ZERO scratch:
//  - A expanded chunk-by-chunk (one intx4 live, not 4)
//  - single store base pointer + immediate offsets r*1024B (all 16 tile rows
//    share bb since nw%16==0; rows are 1KB apart), pb += 32KB per t
//  - t=95 peeled (out1 epilogue out of the hot loop)
// C/D layout 16x16: col=lane&15, row=(lane>>4)*4+reg (dtype-independent).
// A/B k-packing self-consistent (k = 64c + 16g + bytepos).
// Membrane update in exact reference fp32 op order (bit-identical to R6).
// ---------------------------------------------------------------------------
__global__ __launch_bounds__(256, 2) void rnn_kernel(
    const unsigned char* __restrict__ s0b,
    const signed char* __restrict__ Bw8,
    const float* __restrict__ b_rnn,
    float* __restrict__ out0,
    float* __restrict__ out1)
{
    const int tid  = threadIdx.x;
    const int wid  = tid >> 6, lane = tid & 63;
    const int m    = lane & 15, g = lane >> 4;
    const int job  = blockIdx.x * 4 + wid;          // 2048 jobs
    const int rt   = job >> 4;                      // 128 row-tiles
    const int nw   = rt * 16;
    const int o0   = (job & 15) * 16;               // 16 col-tiles

    // --- B fragments (loop-invariant): 4 limbs x 4 chunks x int4 = 64 VGPRs
    intx4 bfrag[4][4];
#pragma unroll
    for (int l = 0; l < 4; ++l)
#pragma unroll
        for (int c = 0; c < 4; ++c)
            bfrag[l][c] = *(const intx4*)(Bw8 + ((size_t)(o0 + m) * 4 + l) * 256
                                               + c * 64 + g * 16);
    const float bias = b_rnn[256 + o0 + m];

    // --- single store base (C/D row = nw + g*4 + r, all rows share bb) ---
    float* pb = out0 + ((size_t)(nw >> 5) * 96) * 8192
                     + (size_t)((nw & 31) + g * 4) * 256 + o0 + m;

    // --- mask stream: lane reads uint2 at row*32 + 8g, prefetched 2 ahead ---
    const unsigned char* mp = s0b + ((size_t)(nw + m)) * 32 + 8 * g;
    uint2 m0 = *(const uint2*)(mp);
    uint2 m1 = *(const uint2*)(mp + 65536);

    floatx4 v = {0.f, 0.f, 0.f, 0.f};

    #define STEP_MFMA(MASK, ACC0, ACC1, ACC2, ACC3)                            \
    do {                                                                       \
        unsigned int hw_[4] = { (MASK).x & 0xFFFFu, (MASK).x >> 16,            \
                                (MASK).y & 0xFFFFu, (MASK).y >> 16 };          \
        _Pragma("unroll")                                                      \
        for (int c = 0; c < 4; ++c) {                                          \
            unsigned int h_ = hw_[c];                                          \
            intx4 a_;                                                          \
            a_.x = (int)((( h_        & 0xFu) * 0x00204081u) & 0x01010101u);   \
            a_.y = (int)((((h_ >> 4)  & 0xFu) * 0x00204081u) & 0x01010101u);   \
            a_.z = (int)((((h_ >> 8)  & 0xFu) * 0x00204081u) & 0x01010101u);   \
            a_.w = (int)((((h_ >> 12) & 0xFu) * 0x00204081u) & 0x01010101u);   \
            ACC0 = __builtin_amdgcn_mfma_i32_16x16x64_i8(a_, bfrag[0][c], ACC0, 0, 0, 0); \
            ACC1 = __builtin_amdgcn_mfma_i32_16x16x64_i8(a_, bfrag[1][c], ACC1, 0, 0, 0); \
            ACC2 = __builtin_amdgcn_mfma_i32_16x16x64_i8(a_, bfrag[2][c], ACC2, 0, 0, 0); \
            ACC3 = __builtin_amdgcn_mfma_i32_16x16x64_i8(a_, bfrag[3][c], ACC3, 0, 0, 0); \
        }                                                                      \
    } while (0)

    for (int t = 0; t < 95; ++t) {
        uint2 nxt = m1;
        if (t < 94)
            m1 = *(const uint2*)(mp + (size_t)(t + 2) * 65536);

        intx4 acc0 = {0,0,0,0}, acc1 = {0,0,0,0}, acc2 = {0,0,0,0}, acc3 = {0,0,0,0};
        STEP_MFMA(m0, acc0, acc1, acc2, acc3);

        // exact limb combine + membrane update (reference fp32 op order)
#pragma unroll
        for (int r = 0; r < 4; ++r) {
            int a01 = acc0[r] * 128 + acc1[r];      // exact, |.| < 2^21
            int a23 = acc2[r] * 128 + acc3[r];
            double dd = (double)a01 * 16384.0 + (double)a23;   // exact
            float cur = (float)(dd * 7.450580596923828125e-9) + bias;  // *2^-27
            float vv = v[r];
            vv = vv + (cur - vv) * 0.5f;
            float s = ((vv - 1.0f) >= 0.0f) ? 1.0f : 0.0f;
            v[r] = vv * (1.0f - s);
            pb[r * 256] = s;                        // rows 1KB apart, imm offset
        }
        pb += 8192;                                 // next t-slice
        m0 = nxt;
    }

    // --- peeled t = 95: same math + out1 stores ---
    {
        intx4 acc0 = {0,0,0,0}, acc1 = {0,0,0,0}, acc2 = {0,0,0,0}, acc3 = {0,0,0,0};
        STEP_MFMA(m0, acc0, acc1, acc2, acc3);
#pragma unroll
        for (int r = 0; r < 4; ++r) {
            int a01 = acc0[r] * 128 + acc1[r];
            int a23 = acc2[r] * 128 + acc3[r];
            double dd = (double)a01 * 16384.0 + (double)a23;
            float cur = (float)(dd * 7.450580596923828125e-9) + bias;
            float vv = v[r];
            vv = vv + (cur - vv) * 0.5f;
            float s = ((vv - 1.0f) >= 0.0f) ? 1.0f : 0.0f;
            pb[r * 256] = s;
            out1[(size_t)(nw + g * 4 + r) * 256 + o0 + m] = s;
        }
    }
    #undef STEP_MFMA
}

// ---------------------------------------------------------------------------
extern "C" void kernel_launch(void* const* d_in, const int* in_sizes, int n_in,
                              void* d_out, int out_size, void* d_ws, size_t ws_size,
                              hipStream_t stream) {
    const float* inputs = (const float*)d_in[0];   // [64,96,32]
    const float* w_enc  = (const float*)d_in[1];   // [256,1,3]
    const float* b_enc  = (const float*)d_in[2];   // [256]
    const float* w_rnn  = (const float*)d_in[3];   // [2,256,256]
    const float* b_rnn  = (const float*)d_in[4];   // [2,256]

    float* out0 = (float*)d_out;                       // [64,96,8192]
    float* out1 = out0 + (size_t)64 * 96 * 8192;       // [64,8192]

    char* ws = (char*)d_ws;
    double*      Wd  = (double*)(ws);                  //  768 doubles  [0,6144)
    double*      C0d = (double*)(ws + 6144);           //  256 doubles  [6144,8192)
    signed char* Bw8 = (signed char*)(ws + 8192);      //  256*4*256 i8 [8192,270336)
    unsigned char* s0b = (unsigned char*)(ws + 270336);// 6291456 bytes of spike bits

    prep_kernel<<<256, 64, 0, stream>>>(w_enc, b_enc, w_rnn, b_rnn, Wd, C0d, Bw8);
    enc_kernel<<<2048, 256, 0, stream>>>(inputs, Wd, C0d, s0b);
    rnn_kernel<<<512, 256, 0, stream>>>(s0b, Bw8, b_rnn, out0, out1);
}

// Round 8
// 257.932 us; speedup vs baseline: 1.1451x; 1.0114x over previous
//
#include <hip/hip_runtime.h>
#include <hip/hip_bf16.h>
#include <stdint.h>

// Problem constants: B=64, L=96, C=32, H=256, NL=2, K=3, TAU=2, VTH=1
// n = b*32 + c indexes the B*C=2048 "rows"; layer width H=256.

using floatx4 = __attribute__((ext_vector_type(4))) float;
using intx4   = __attribute__((ext_vector_type(4))) int;

// ---------------------------------------------------------------------------
// prep: per output-neuron o (256 blocks x 64 threads)
//  - W[o][k]  = sum_i w0[o,i]*w_enc[i,k]   (fp64)
//  - C0[o]    = sum_i b_enc[i]*w0[o,i] + b_rnn[0][o]  (fp64)
//  - i8 4-limb digit planes of w1: q=rn(w*2^27), q=((d0*128+d1)*128+d2)*128+d3,
//    digits in [-64,63]. Bw8[o][l][k] = d_l of w1[o][k]. EXACT (|w|<1).
// ---------------------------------------------------------------------------
__global__ void prep_kernel(const float* __restrict__ w_enc,
                            const float* __restrict__ b_enc,
                            const float* __restrict__ w_rnn,
                            const float* __restrict__ b_rnn,
                            double* __restrict__ Wd,
                            double* __restrict__ C0d,
                            signed char* __restrict__ Bw8)
{
    const int o = blockIdx.x;
    const int lane = threadIdx.x;   // 64 threads
    const float4 w0v = *(const float4*)(w_rnn + (size_t)o * 256 + lane * 4);
    double a0 = 0.0, a1 = 0.0, a2 = 0.0, ab = 0.0;
#pragma unroll
    for (int e = 0; e < 4; ++e) {
        const int i = lane * 4 + e;
        const double wv = (double)(((const float*)&w0v)[e]);
        a0 += wv * (double)w_enc[i * 3 + 0];
        a1 += wv * (double)w_enc[i * 3 + 1];
        a2 += wv * (double)w_enc[i * 3 + 2];
        ab += wv * (double)b_enc[i];
    }
    for (int off = 32; off > 0; off >>= 1) {
        a0 += __shfl_down(a0, off, 64);
        a1 += __shfl_down(a1, off, 64);
        a2 += __shfl_down(a2, off, 64);
        ab += __shfl_down(ab, off, 64);
    }
    if (lane == 0) {
        Wd[o * 3 + 0] = a0;
        Wd[o * 3 + 1] = a1;
        Wd[o * 3 + 2] = a2;
        C0d[o] = ab + (double)b_rnn[o];
    }
    // i8 digit planes of w1 (layer-1), 4 consecutive k per lane
    const float4 w1v = *(const float4*)(w_rnn + 65536 + (size_t)o * 256 + lane * 4);
    unsigned int pack[4] = {0u, 0u, 0u, 0u};   // pack[l]: digits for e=0..3
#pragma unroll
    for (int e = 0; e < 4; ++e) {
        float f = ((const float*)&w1v)[e];
        int q = __double2int_rn((double)f * 134217728.0);   // w * 2^27, |q| <= 2^27
        int d3 = ((q + 64) & 127) - 64;  q = (q - d3) >> 7;
        int d2 = ((q + 64) & 127) - 64;  q = (q - d2) >> 7;
        int d1 = ((q + 64) & 127) - 64;  q = (q - d1) >> 7;
        int d0 = q;                       // |d0| <= 64
        pack[0] |= ((unsigned int)(d0 & 0xFF)) << (8 * e);
        pack[1] |= ((unsigned int)(d1 & 0xFF)) << (8 * e);
        pack[2] |= ((unsigned int)(d2 & 0xFF)) << (8 * e);
        pack[3] |= ((unsigned int)(d3 & 0xFF)) << (8 * e);
    }
#pragma unroll
    for (int l = 0; l < 4; ++l)
        *(unsigned int*)(Bw8 + ((size_t)o * 4 + l) * 256 + lane * 4) = pack[l];
}

// ---------------------------------------------------------------------------
// enc: layer-0 full scan. 2048 blocks x 256 threads. cur0 in fp64 (correctly
// rounded), membrane chain in exact reference fp32 op order. Spike mask rows
// stored HALFWORD-TRANSPOSED: row (t,n) is 32B; global halfword h=i/16
// (h = 4*wave + j) lands at byte offset 8*j + 2*wave. Then rnn lane (g,m)
// reads one aligned uint2 at +8g = halfwords {4c+g : c=0..3} = exactly the
// k-bits its 4 MFMA chunks need.
// ---------------------------------------------------------------------------
__global__ void enc_kernel(const float* __restrict__ inputs,
                           const double* __restrict__ Wd,
                           const double* __restrict__ C0d,
                           unsigned char* __restrict__ s0b)
{
    const int n = blockIdx.x;
    const int tidx = threadIdx.x;
    const int b = n >> 5, c = n & 31;
    __shared__ float xr[98];
    if (tidx < 96)       xr[tidx + 1] = inputs[((size_t)b * 96 + tidx) * 32 + c];
    else if (tidx == 96) xr[0]  = 0.0f;
    else if (tidx == 97) xr[97] = 0.0f;
    __syncthreads();
    const double W0 = Wd[tidx * 3], W1 = Wd[tidx * 3 + 1], W2 = Wd[tidx * 3 + 2];
    const double c0 = C0d[tidx];
    const int wid = tidx >> 6, lane = tidx & 63;
    float v = 0.0f;
    for (int t = 0; t < 96; ++t) {
        float cur = (float)((double)xr[t] * W0 + (double)xr[t + 1] * W1 +
                            (double)xr[t + 2] * W2 + c0);
        float vv = v + (cur - v) * 0.5f;
        int sp = (vv - 1.0f) >= 0.0f;
        v = sp ? 0.0f : vv;
        unsigned long long bal = __ballot(sp);
        if ((lane & 15) == 0) {
            const int j = lane >> 4;
            *(unsigned short*)(s0b + ((size_t)t * 2048 + n) * 32 + 8 * j + 2 * wid)
                = (unsigned short)(bal >> (16 * j));
        }
    }
}

// ---------------------------------------------------------------------------
// rnn: layer-1, i8 4-limb exact MFMA, NO LDS, NO barriers. 2048 independent
// wave-jobs (512 blocks x 4 waves); wave = 16 rows x 16 cols; the 4 waves of
// a block share the same 16 rows (L1 mask reuse).
// R8 changes (bit-identical numerics to R6/R7):
//  - MFMA operands SWAPPED: weights in the A slot, spikes in the B slot.
//    Fragment fetches are unchanged (k-packing symmetric); C/D flips so lane
//    (g,m) holds 4 CONSECUTIVE out-cols (o0+4g..+3) of spike-row nw+m -> the
//    per-step store is ONE global_store_dwordx4 (16B/lane, 1KB/wave) instead
//    of four scattered dword stores.
//  - fp32 limb combine replaces fp64: cur_q = fmaf((float)a01, 2^-13,
//    (float)a23 * 2^-27). (float)a01/(float)a23 exact (<2^22 < 2^24);
//    products are pow-2 scales (exact); fmaf = single rounding of the exact
//    total == the fp64 path's RN(exact) -> BIT-IDENTICAL.
//  - mask buffer padded to 98 t-slots -> branchless 2-ahead prefetch.
// C/D layout 16x16: "row"(M)=(lane>>4)*4+reg -> out-col; "col"(N)=lane&15 ->
// spike-row. Membrane update in exact reference fp32 op order.
// ---------------------------------------------------------------------------
__global__ __launch_bounds__(256, 2) void rnn_kernel(
    const unsigned char* __restrict__ s0b,
    const signed char* __restrict__ Bw8,
    const float* __restrict__ b_rnn,
    float* __restrict__ out0,
    float* __restrict__ out1)
{
    const int tid  = threadIdx.x;
    const int wid  = tid >> 6, lane = tid & 63;
    const int m    = lane & 15, g = lane >> 4;
    const int job  = blockIdx.x * 4 + wid;          // 2048 jobs
    const int rt   = job >> 4;                      // 128 row-tiles
    const int nw   = rt * 16;
    const int o0   = (job & 15) * 16;               // 16 col-tiles

    // --- weight A-fragments (loop-invariant): 4 limbs x 4 chunks = 64 VGPRs
    intx4 bfrag[4][4];
#pragma unroll
    for (int l = 0; l < 4; ++l)
#pragma unroll
        for (int c = 0; c < 4; ++c)
            bfrag[l][c] = *(const intx4*)(Bw8 + ((size_t)(o0 + m) * 4 + l) * 256
                                               + c * 64 + g * 16);
    // per-lane bias for out-cols o0+4g .. o0+4g+3
    const float4 biasv = *(const float4*)(b_rnn + 256 + o0 + g * 4);

    // --- store base: spike-row nw+m, col o0+4g (16B-aligned) ---
    float* pb = out0 + ((size_t)(nw >> 5) * 96) * 8192
                     + (size_t)((nw & 31) + m) * 256 + o0 + g * 4;

    // --- mask stream: lane reads uint2 at row*32 + 8g, prefetched 2 ahead ---
    const unsigned char* mp = s0b + ((size_t)(nw + m)) * 32 + 8 * g;
    uint2 m0 = *(const uint2*)(mp);
    uint2 m1 = *(const uint2*)(mp + 65536);

    floatx4 v = {0.f, 0.f, 0.f, 0.f};

    #define STEP_MFMA(MASK, ACC0, ACC1, ACC2, ACC3)                            \
    do {                                                                       \
        unsigned int hw_[4] = { (MASK).x & 0xFFFFu, (MASK).x >> 16,            \
                                (MASK).y & 0xFFFFu, (MASK).y >> 16 };          \
        _Pragma("unroll")                                                      \
        for (int c = 0; c < 4; ++c) {                                          \
            unsigned int h_ = hw_[c];                                          \
            intx4 a_;                                                          \
            a_.x = (int)((( h_        & 0xFu) * 0x00204081u) & 0x01010101u);   \
            a_.y = (int)((((h_ >> 4)  & 0xFu) * 0x00204081u) & 0x01010101u);   \
            a_.z = (int)((((h_ >> 8)  & 0xFu) * 0x00204081u) & 0x01010101u);   \
            a_.w = (int)((((h_ >> 12) & 0xFu) * 0x00204081u) & 0x01010101u);   \
            ACC0 = __builtin_amdgcn_mfma_i32_16x16x64_i8(bfrag[0][c], a_, ACC0, 0, 0, 0); \
            ACC1 = __builtin_amdgcn_mfma_i32_16x16x64_i8(bfrag[1][c], a_, ACC1, 0, 0, 0); \
            ACC2 = __builtin_amdgcn_mfma_i32_16x16x64_i8(bfrag[2][c], a_, ACC2, 0, 0, 0); \
            ACC3 = __builtin_amdgcn_mfma_i32_16x16x64_i8(bfrag[3][c], a_, ACC3, 0, 0, 0); \
        }                                                                      \
    } while (0)

    for (int t = 0; t < 95; ++t) {
        uint2 nxt = m1;
        m1 = *(const uint2*)(mp + (size_t)(t + 2) * 65536);   // slots 96/97 padded

        intx4 acc0 = {0,0,0,0}, acc1 = {0,0,0,0}, acc2 = {0,0,0,0}, acc3 = {0,0,0,0};
        STEP_MFMA(m0, acc0, acc1, acc2, acc3);

        // exact fp32 limb combine + membrane update (reference fp32 op order)
        float4 sv;
#pragma unroll
        for (int r = 0; r < 4; ++r) {
            int a01 = acc0[r] * 128 + acc1[r];      // exact, |.| < 2^22
            int a23 = acc2[r] * 128 + acc3[r];
            float cur = fmaf((float)a01, 0x1p-13f, (float)a23 * 0x1p-27f)
                        + ((const float*)&biasv)[r];
            float vv = v[r];
            vv = vv + (cur - vv) * 0.5f;
            float s = ((vv - 1.0f) >= 0.0f) ? 1.0f : 0.0f;
            v[r] = vv * (1.0f - s);
            ((float*)&sv)[r] = s;
        }
        *(float4*)pb = sv;                          // 16B/lane, 1KB/wave
        pb += 8192;
        m0 = nxt;
    }

    // --- peeled t = 95: same math + out1 stores ---
    {
        intx4 acc0 = {0,0,0,0}, acc1 = {0,0,0,0}, acc2 = {0,0,0,0}, acc3 = {0,0,0,0};
        STEP_MFMA(m0, acc0, acc1, acc2, acc3);
        float4 sv;
#pragma unroll
        for (int r = 0; r < 4; ++r) {
            int a01 = acc0[r] * 128 + acc1[r];
            int a23 = acc2[r] * 128 + acc3[r];
            float cur = fmaf((float)a01, 0x1p-13f, (float)a23 * 0x1p-27f)
                        + ((const float*)&biasv)[r];
            float vv = v[r];
            vv = vv + (cur - vv) * 0.5f;
            float s = ((vv - 1.0f) >= 0.0f) ? 1.0f : 0.0f;
            ((float*)&sv)[r] = s;
        }
        *(float4*)pb = sv;
        *(float4*)(out1 + (size_t)(nw + m) * 256 + o0 + g * 4) = sv;
    }
    #undef STEP_MFMA
}

// ---------------------------------------------------------------------------
extern "C" void kernel_launch(void* const* d_in, const int* in_sizes, int n_in,
                              void* d_out, int out_size, void* d_ws, size_t ws_size,
                              hipStream_t stream) {
    const float* inputs = (const float*)d_in[0];   // [64,96,32]
    const float* w_enc  = (const float*)d_in[1];   // [256,1,3]
    const float* b_enc  = (const float*)d_in[2];   // [256]
    const float* w_rnn  = (const float*)d_in[3];   // [2,256,256]
    const float* b_rnn  = (const float*)d_in[4];   // [2,256]

    float* out0 = (float*)d_out;                       // [64,96,8192]
    float* out1 = out0 + (size_t)64 * 96 * 8192;       // [64,8192]

    char* ws = (char*)d_ws;
    double*      Wd  = (double*)(ws);                  //  768 doubles  [0,6144)
    double*      C0d = (double*)(ws + 6144);           //  256 doubles  [6144,8192)
    signed char* Bw8 = (signed char*)(ws + 8192);      //  256*4*256 i8 [8192,270336)
    unsigned char* s0b = (unsigned char*)(ws + 270336);// 98*65536 B spike bits (2 pad slots)

    prep_kernel<<<256, 64, 0, stream>>>(w_enc, b_enc, w_rnn, b_rnn, Wd, C0d, Bw8);
    enc_kernel<<<2048, 256, 0, stream>>>(inputs, Wd, C0d, s0b);
    rnn_kernel<<<512, 256, 0, stream>>>(s0b, Bw8, b_rnn, out0, out1);
}